// Round 2
// baseline (261.360 us; speedup 1.0000x reference)
//
#include <hip/hip_runtime.h>

#define D 128
#define NCLS 3
#define MAXREP 8

typedef float f32x4 __attribute__((ext_vector_type(4)));

// ws layout (dwords): [0 .. rep*384-1] per-class sums (rep replicas of 3x128),
//                     [rep*384 .. rep*384+rep*3-1] counts (uint),
//                     [last] done counter (uint)

__global__ __launch_bounds__(256) void center_fused_kernel(
    const float* __restrict__ feat, const int* __restrict__ labels,
    float* __restrict__ ws, int rep, unsigned int nblocks,
    float* __restrict__ out, int N, int tail)
{
    __shared__ float s_sum[NCLS * D];
    __shared__ unsigned int s_cnt[NCLS];
    __shared__ unsigned int s_last;
    __shared__ float s_cntf[NCLS];

    float* __restrict__ sums = ws;
    unsigned int* __restrict__ counts = (unsigned int*)(ws + rep * NCLS * D);
    unsigned int* __restrict__ done = counts + rep * NCLS;

    const int t = threadIdx.x;
    for (int i = t; i < NCLS * D; i += 256) s_sum[i] = 0.0f;
    if (t < NCLS) s_cnt[t] = 0u;
    __syncthreads();

    const int col8 = t & 15;   // which 32B chunk (2 float4s) within the 128-wide row
    const int rsub = t >> 4;   // 0..15 row slot within the block's 16-row stripe
    const f32x4* __restrict__ f4 = (const f32x4*)feat;

    f32x4 z = {0.f, 0.f, 0.f, 0.f};
    f32x4 a0 = z, a1 = z, a2 = z, b0 = z, b1 = z, b2 = z;
    unsigned int c0 = 0u, c1 = 0u, c2 = 0u;

    for (long long row = (long long)blockIdx.x * 16 + rsub; row < N;
         row += (long long)gridDim.x * 16) {
        const int lab = labels[row];
        const long long base = row * 32 + col8 * 2;
        const f32x4 v0 = __builtin_nontemporal_load(f4 + base);
        const f32x4 v1 = __builtin_nontemporal_load(f4 + base + 1);
        const float m0 = (lab == 0) ? 1.0f : 0.0f;
        const float m1 = (lab == 1) ? 1.0f : 0.0f;
        const float m2 = (lab == 2) ? 1.0f : 0.0f;
        a0 += v0 * m0; a1 += v0 * m1; a2 += v0 * m2;
        b0 += v1 * m0; b1 += v1 * m1; b2 += v1 * m2;
        c0 += (lab == 0); c1 += (lab == 1); c2 += (lab == 2);
    }

    // block-level reduce into LDS
    const int cbase = col8 * 8;
    #pragma unroll
    for (int j = 0; j < 4; j++) {
        atomicAdd(&s_sum[0 * D + cbase + j], a0[j]);
        atomicAdd(&s_sum[1 * D + cbase + j], a1[j]);
        atomicAdd(&s_sum[2 * D + cbase + j], a2[j]);
        atomicAdd(&s_sum[0 * D + cbase + 4 + j], b0[j]);
        atomicAdd(&s_sum[1 * D + cbase + 4 + j], b1[j]);
        atomicAdd(&s_sum[2 * D + cbase + 4 + j], b2[j]);
    }
    if (col8 == 0) {  // one counting thread per row slot
        atomicAdd(&s_cnt[0], c0);
        atomicAdd(&s_cnt[1], c1);
        atomicAdd(&s_cnt[2], c2);
    }
    __syncthreads();

    // one global atomic per element per block, into this block's replica
    float* msums = sums + (blockIdx.x & (rep - 1)) * NCLS * D;
    unsigned int* mcnt = counts + (blockIdx.x & (rep - 1)) * NCLS;
    for (int i = t; i < NCLS * D; i += 256) atomicAdd(&msums[i], s_sum[i]);
    if (t < NCLS) atomicAdd(&mcnt[t], s_cnt[t]);

    // ---- last-block finalization ----
    __threadfence();
    __syncthreads();
    if (t == 0) s_last = (atomicAdd(done, 1u) == nblocks - 1u) ? 1u : 0u;
    __syncthreads();
    if (!s_last) return;

    // counts (read via atomic to stay coherent across XCDs)
    if (t < NCLS) {
        float c = 0.f;
        for (int r = 0; r < rep; r++) c += (float)atomicAdd(&counts[r * NCLS + t], 0u);
        s_cntf[t] = c;
    }
    __syncthreads();

    float center[NCLS];
    #pragma unroll
    for (int k = 0; k < NCLS; k++) center[k] = 0.0f;
    if (t < D) {
        #pragma unroll
        for (int k = 0; k < NCLS; k++) {
            float s = 0.f;
            for (int r = 0; r < rep; r++)
                s += atomicAdd(&sums[r * NCLS * D + k * D + t], 0.0f);
            center[k] = s / s_cntf[k];
        }
    }

    // norm^2 reduction: shuffle within each wave, combine 4 wave partials in LDS
    const int lane = t & 63, wv = t >> 6;
    #pragma unroll
    for (int k = 0; k < NCLS; k++) {
        float x = center[k] * center[k];   // 0 for t >= 128
        #pragma unroll
        for (int off = 32; off; off >>= 1) x += __shfl_down(x, off, 64);
        if (lane == 0) s_sum[k * 4 + wv] = x;
    }
    __syncthreads();

    if (t < D) {
        #pragma unroll
        for (int k = 0; k < NCLS; k++) {
            const float norm = sqrtf(s_sum[k * 4 + 0] + s_sum[k * 4 + 1] +
                                     s_sum[k * 4 + 2] + s_sum[k * 4 + 3]);
            out[k * D + t] = center[k] / fmaxf(norm, 1e-12f);
        }
    }
    // second tuple output: target = arange(NUM_CLASSES)
    if (t < tail) out[NCLS * D + t] = (float)t;
}

extern "C" void kernel_launch(void* const* d_in, const int* in_sizes, int n_in,
                              void* d_out, int out_size, void* d_ws, size_t ws_size,
                              hipStream_t stream) {
    const float* feat = (const float*)d_in[0];
    const int* labels = (const int*)d_in[1];
    const int N = in_sizes[1];

    int rep = 1;
    const size_t need8 = ((size_t)MAXREP * NCLS * D + MAXREP * NCLS + 1) * 4;
    if (ws_size >= need8) rep = MAXREP;

    const size_t zbytes = ((size_t)rep * NCLS * D + rep * NCLS + 1) * 4;
    hipMemsetAsync(d_ws, 0, zbytes, stream);

    int tail = out_size - NCLS * D;
    if (tail < 0) tail = 0;
    if (tail > D) tail = D;

    const unsigned int grid = 2048;
    center_fused_kernel<<<grid, 256, 0, stream>>>(feat, labels, (float*)d_ws, rep,
                                                  grid, (float*)d_out, N, tail);
}

// Round 3
// 257.596 us; speedup vs baseline: 1.0146x; 1.0146x over previous
//
#include <hip/hip_runtime.h>

#define D 128
#define NCLS 3
#define MAXREP 8
#define UNROLL 4

typedef float f32x4 __attribute__((ext_vector_type(4)));

// ws layout (dwords): [0 .. rep*384-1] per-class sums (rep replicas of 3x128),
//                     [rep*384 .. rep*384+rep*3-1] counts (uint),
//                     [last] done counter (uint)

__global__ __launch_bounds__(256) void center_fused_kernel(
    const float* __restrict__ feat, const int* __restrict__ labels,
    float* __restrict__ ws, int rep, unsigned int nblocks,
    float* __restrict__ out, int N, int tail)
{
    __shared__ float s_sum[NCLS * D];
    __shared__ unsigned int s_cnt[NCLS];
    __shared__ unsigned int s_last;
    __shared__ float s_cntf[NCLS];

    float* __restrict__ sums = ws;
    unsigned int* __restrict__ counts = (unsigned int*)(ws + rep * NCLS * D);
    unsigned int* __restrict__ done = counts + rep * NCLS;

    const int t = threadIdx.x;
    for (int i = t; i < NCLS * D; i += 256) s_sum[i] = 0.0f;
    if (t < NCLS) s_cnt[t] = 0u;
    __syncthreads();

    const int col4 = t & 31;   // which float4 (of 32) within the 128-wide row
    const int rsub = t >> 5;   // 0..7 row slot within an 8-row stripe
    const f32x4* __restrict__ f4 = (const f32x4*)feat;

    const f32x4 z = {0.f, 0.f, 0.f, 0.f};
    f32x4 a0 = z, a1 = z, a2 = z;
    unsigned int c0 = 0u, c1 = 0u, c2 = 0u;

    const long long stride = (long long)gridDim.x * (8 * UNROLL);

    for (long long base = (long long)blockIdx.x * (8 * UNROLL) + rsub; base < N;
         base += stride) {
        long long r[UNROLL];
        int lab[UNROLL];
        float valid[UNROLL];
        f32x4 v[UNROLL];
        // issue all loads first (independent -> in flight together)
        #pragma unroll
        for (int u = 0; u < UNROLL; u++) {
            const long long ru = base + u * 8;
            const bool ok = ru < N;
            r[u] = ok ? ru : 0;
            valid[u] = ok ? 1.0f : 0.0f;
            lab[u] = labels[r[u]];
            v[u] = f4[r[u] * 32 + col4];
        }
        #pragma unroll
        for (int u = 0; u < UNROLL; u++) {
            const float m0 = (lab[u] == 0) ? valid[u] : 0.0f;
            const float m1 = (lab[u] == 1) ? valid[u] : 0.0f;
            const float m2 = (lab[u] == 2) ? valid[u] : 0.0f;
            a0 += v[u] * m0;
            a1 += v[u] * m1;
            a2 += v[u] * m2;
            c0 += (lab[u] == 0) && (valid[u] != 0.0f);
            c1 += (lab[u] == 1) && (valid[u] != 0.0f);
            c2 += (lab[u] == 2) && (valid[u] != 0.0f);
        }
    }

    // block-level reduce into LDS
    const int cbase = col4 * 4;
    #pragma unroll
    for (int j = 0; j < 4; j++) {
        atomicAdd(&s_sum[0 * D + cbase + j], a0[j]);
        atomicAdd(&s_sum[1 * D + cbase + j], a1[j]);
        atomicAdd(&s_sum[2 * D + cbase + j], a2[j]);
    }
    if (col4 == 0) {  // one counting thread per row slot
        atomicAdd(&s_cnt[0], c0);
        atomicAdd(&s_cnt[1], c1);
        atomicAdd(&s_cnt[2], c2);
    }
    __syncthreads();

    // one global atomic per element per block, into this block's replica
    float* msums = sums + (blockIdx.x & (rep - 1)) * NCLS * D;
    unsigned int* mcnt = counts + (blockIdx.x & (rep - 1)) * NCLS;
    for (int i = t; i < NCLS * D; i += 256) atomicAdd(&msums[i], s_sum[i]);
    if (t < NCLS) atomicAdd(&mcnt[t], s_cnt[t]);

    // ---- last-block finalization ----
    __threadfence();
    __syncthreads();
    if (t == 0) s_last = (atomicAdd(done, 1u) == nblocks - 1u) ? 1u : 0u;
    __syncthreads();
    if (!s_last) return;

    // counts (read via atomic to stay coherent across XCDs)
    if (t < NCLS) {
        float c = 0.f;
        for (int rp = 0; rp < rep; rp++) c += (float)atomicAdd(&counts[rp * NCLS + t], 0u);
        s_cntf[t] = c;
    }
    __syncthreads();

    float center[NCLS];
    #pragma unroll
    for (int k = 0; k < NCLS; k++) center[k] = 0.0f;
    if (t < D) {
        #pragma unroll
        for (int k = 0; k < NCLS; k++) {
            float s = 0.f;
            for (int rp = 0; rp < rep; rp++)
                s += atomicAdd(&sums[rp * NCLS * D + k * D + t], 0.0f);
            center[k] = s / s_cntf[k];
        }
    }

    // norm^2 reduction: shuffle within each wave, combine 4 wave partials in LDS
    const int lane = t & 63, wv = t >> 6;
    #pragma unroll
    for (int k = 0; k < NCLS; k++) {
        float x = center[k] * center[k];   // 0 for t >= 128
        #pragma unroll
        for (int off = 32; off; off >>= 1) x += __shfl_down(x, off, 64);
        if (lane == 0) s_sum[k * 4 + wv] = x;
    }
    __syncthreads();

    if (t < D) {
        #pragma unroll
        for (int k = 0; k < NCLS; k++) {
            const float norm = sqrtf(s_sum[k * 4 + 0] + s_sum[k * 4 + 1] +
                                     s_sum[k * 4 + 2] + s_sum[k * 4 + 3]);
            out[k * D + t] = center[k] / fmaxf(norm, 1e-12f);
        }
    }
    // second tuple output: target = arange(NUM_CLASSES)
    if (t < tail) out[NCLS * D + t] = (float)t;
}

extern "C" void kernel_launch(void* const* d_in, const int* in_sizes, int n_in,
                              void* d_out, int out_size, void* d_ws, size_t ws_size,
                              hipStream_t stream) {
    const float* feat = (const float*)d_in[0];
    const int* labels = (const int*)d_in[1];
    const int N = in_sizes[1];

    int rep = 1;
    const size_t need8 = ((size_t)MAXREP * NCLS * D + MAXREP * NCLS + 1) * 4;
    if (ws_size >= need8) rep = MAXREP;

    const size_t zbytes = ((size_t)rep * NCLS * D + rep * NCLS + 1) * 4;
    hipMemsetAsync(d_ws, 0, zbytes, stream);

    int tail = out_size - NCLS * D;
    if (tail < 0) tail = 0;
    if (tail > D) tail = D;

    const unsigned int grid = 2048;
    center_fused_kernel<<<grid, 256, 0, stream>>>(feat, labels, (float*)d_ws, rep,
                                                  grid, (float*)d_out, N, tail);
}

// Round 4
// 74.401 us; speedup vs baseline: 3.5128x; 3.4622x over previous
//
#include <hip/hip_runtime.h>

#define D 128
#define NCLS 3
#define REP 8

typedef float f32x4 __attribute__((ext_vector_type(4)));

// ws layout (dwords): [0 .. REP*384-1] per-class sums (REP replicas of 3x128),
//                     [REP*384 .. REP*384+REP*3-1] counts (uint)

__global__ __launch_bounds__(256) void class_sum_kernel(
    const float* __restrict__ feat, const int* __restrict__ labels,
    float* __restrict__ sums, unsigned int* __restrict__ counts, int N)
{
    __shared__ float s_sum[NCLS * D];
    __shared__ unsigned int s_cnt[NCLS];
    const int t = threadIdx.x;

    for (int i = t; i < NCLS * D; i += 256) s_sum[i] = 0.0f;
    if (t < NCLS) s_cnt[t] = 0u;
    __syncthreads();

    const int col4 = t & 31;   // which float4 (of 32) within the 128-wide row
    const int rsub = t >> 5;   // 0..7 row slot within an 8-row stripe
    const f32x4* __restrict__ f4 = (const f32x4*)feat;

    const f32x4 z = {0.f, 0.f, 0.f, 0.f};
    f32x4 a0 = z, a1 = z, a2 = z;
    unsigned int c0 = 0u, c1 = 0u, c2 = 0u;

    // 16 rows per block per iteration: rows base+rsub and base+rsub+8.
    const long long stride = (long long)gridDim.x * 16;
    for (long long r0 = (long long)blockIdx.x * 16 + rsub; r0 < N; r0 += stride) {
        const long long r1c = r0 + 8;
        const bool ok1 = r1c < N;          // r0 < N guaranteed by loop condition
        const long long r1 = ok1 ? r1c : r0;
        // issue both label + both feature loads before any use
        const int lab0 = labels[r0];
        const int lab1 = labels[r1];
        const f32x4 v0 = f4[r0 * 32 + col4];
        const f32x4 v1 = f4[r1 * 32 + col4];

        const float f1 = ok1 ? 1.0f : 0.0f;
        const float m00 = (lab0 == 0) ? 1.0f : 0.0f;
        const float m01 = (lab0 == 1) ? 1.0f : 0.0f;
        const float m02 = (lab0 == 2) ? 1.0f : 0.0f;
        const float m10 = (lab1 == 0) ? f1 : 0.0f;
        const float m11 = (lab1 == 1) ? f1 : 0.0f;
        const float m12 = (lab1 == 2) ? f1 : 0.0f;
        a0 += v0 * m00 + v1 * m10;
        a1 += v0 * m01 + v1 * m11;
        a2 += v0 * m02 + v1 * m12;
        c0 += (lab0 == 0) + (unsigned)((lab1 == 0) && ok1);
        c1 += (lab0 == 1) + (unsigned)((lab1 == 1) && ok1);
        c2 += (lab0 == 2) + (unsigned)((lab1 == 2) && ok1);
    }

    // block-level reduce into LDS
    const int cbase = col4 * 4;
    #pragma unroll
    for (int j = 0; j < 4; j++) {
        atomicAdd(&s_sum[0 * D + cbase + j], a0[j]);
        atomicAdd(&s_sum[1 * D + cbase + j], a1[j]);
        atomicAdd(&s_sum[2 * D + cbase + j], a2[j]);
    }
    if (col4 == 0) {  // one counting thread per row slot
        atomicAdd(&s_cnt[0], c0);
        atomicAdd(&s_cnt[1], c1);
        atomicAdd(&s_cnt[2], c2);
    }
    __syncthreads();

    // one global atomic per element per block, into this block's replica
    float* msums = sums + (blockIdx.x & (REP - 1)) * NCLS * D;
    unsigned int* mcnt = counts + (blockIdx.x & (REP - 1)) * NCLS;
    for (int i = t; i < NCLS * D; i += 256) atomicAdd(&msums[i], s_sum[i]);
    if (t < NCLS) atomicAdd(&mcnt[t], s_cnt[t]);
}

__global__ __launch_bounds__(128) void finalize_kernel(
    const float* __restrict__ sums, const unsigned int* __restrict__ counts,
    float* __restrict__ out, int tail)
{
    __shared__ float s_red[NCLS][2];
    const int t = threadIdx.x;           // 128 threads, one per column
    const int lane = t & 63;
    const int wv = t >> 6;

    float center[NCLS];
    #pragma unroll
    for (int k = 0; k < NCLS; k++) {
        float cnt = 0.0f;
        float s = 0.0f;
        for (int rp = 0; rp < REP; rp++) {
            cnt += (float)counts[rp * NCLS + k];
            s += sums[rp * NCLS * D + k * D + t];
        }
        center[k] = s / cnt;
    }

    #pragma unroll
    for (int k = 0; k < NCLS; k++) {
        float sq = center[k] * center[k];
        #pragma unroll
        for (int off = 32; off > 0; off >>= 1) sq += __shfl_down(sq, off, 64);
        if (lane == 0) s_red[k][wv] = sq;
    }
    __syncthreads();

    #pragma unroll
    for (int k = 0; k < NCLS; k++) {
        const float norm = sqrtf(s_red[k][0] + s_red[k][1]);
        out[k * D + t] = center[k] / fmaxf(norm, 1e-12f);
    }
    // second tuple output: target = arange(NUM_CLASSES), stored as output dtype
    if (t < tail) out[NCLS * D + t] = (float)t;
}

extern "C" void kernel_launch(void* const* d_in, const int* in_sizes, int n_in,
                              void* d_out, int out_size, void* d_ws, size_t ws_size,
                              hipStream_t stream) {
    const float* feat = (const float*)d_in[0];
    const int* labels = (const int*)d_in[1];
    const int N = in_sizes[1];

    float* sums = (float*)d_ws;
    unsigned int* counts = (unsigned int*)((float*)d_ws + REP * NCLS * D);

    // zero the accumulator workspace every call (harness poisons ws once, never restores)
    hipMemsetAsync(d_ws, 0, (REP * NCLS * D + REP * NCLS) * sizeof(float), stream);

    const int grid = 2048;
    class_sum_kernel<<<grid, 256, 0, stream>>>(feat, labels, sums, counts, N);

    int tail = out_size - NCLS * D;
    if (tail < 0) tail = 0;
    if (tail > D) tail = D;
    finalize_kernel<<<1, 128, 0, stream>>>(sums, counts, (float*)d_out, tail);
}

// Round 5
// 64.656 us; speedup vs baseline: 4.0423x; 1.1507x over previous
//
#include <hip/hip_runtime.h>

#define D 128
#define NCLS 3
#define REP 8

typedef float f32x4 __attribute__((ext_vector_type(4)));

// ws layout (dwords): [0 .. REP*384-1] per-class sums (REP replicas of {all,c1,c2} x 128),
//                     [REP*384 .. REP*384+REP*2-1] counts of class1/class2 (uint)

__global__ __launch_bounds__(256) void class_sum_kernel(
    const float* __restrict__ feat, const int* __restrict__ labels,
    float* __restrict__ sums, unsigned int* __restrict__ counts, int N)
{
    __shared__ float s_sum[NCLS * D];   // rows: 0=all, 1=class1, 2=class2
    __shared__ unsigned int s_cnt[2];
    const int t = threadIdx.x;

    for (int i = t; i < NCLS * D; i += 256) s_sum[i] = 0.0f;
    if (t < 2) s_cnt[t] = 0u;
    __syncthreads();

    const int col4 = t & 31;   // which float4 (of 32) within the 128-wide row
    const int rsub = t >> 5;   // 0..7 row slot within an 8-row stripe
    const f32x4* __restrict__ f4 = (const f32x4*)feat;

    const f32x4 z = {0.f, 0.f, 0.f, 0.f};
    f32x4 aAll = z, a1 = z, a2 = z;
    unsigned int c1 = 0u, c2 = 0u;

    // 32 rows per block per iteration: base+rsub+{0,8,16,24}
    const long long step = (long long)gridDim.x * 32;
    for (long long base = (long long)blockIdx.x * 32 + rsub; base < N; base += step) {
        int lab[4];
        f32x4 v[4];
        float ok[4];
        // issue all 8 loads before any use (4 feature dwordx4 + 4 labels)
        #pragma unroll
        for (int u = 0; u < 4; u++) {
            const long long r = base + u * 8;
            const bool okb = r < N;            // base itself always < N
            const long long rc = okb ? r : base;
            ok[u] = okb ? 1.0f : 0.0f;
            lab[u] = labels[rc];
            v[u] = f4[rc * 32 + col4];
        }
        #pragma unroll
        for (int u = 0; u < 4; u++) {
            const float m1 = (lab[u] == 1) ? ok[u] : 0.0f;
            const float m2 = (lab[u] == 2) ? ok[u] : 0.0f;
            aAll += v[u] * ok[u];
            a1   += v[u] * m1;
            a2   += v[u] * m2;
            c1 += (lab[u] == 1) && (ok[u] != 0.0f);
            c2 += (lab[u] == 2) && (ok[u] != 0.0f);
        }
    }

    // block-level reduce into LDS
    const int cbase = col4 * 4;
    #pragma unroll
    for (int j = 0; j < 4; j++) {
        atomicAdd(&s_sum[0 * D + cbase + j], aAll[j]);
        atomicAdd(&s_sum[1 * D + cbase + j], a1[j]);
        atomicAdd(&s_sum[2 * D + cbase + j], a2[j]);
    }
    if (col4 == 0) {  // one counting thread per row slot
        atomicAdd(&s_cnt[0], c1);
        atomicAdd(&s_cnt[1], c2);
    }
    __syncthreads();

    // one global atomic per element per block, into this block's replica
    float* msums = sums + (blockIdx.x & (REP - 1)) * NCLS * D;
    unsigned int* mcnt = counts + (blockIdx.x & (REP - 1)) * 2;
    for (int i = t; i < NCLS * D; i += 256) atomicAdd(&msums[i], s_sum[i]);
    if (t < 2) atomicAdd(&mcnt[t], s_cnt[t]);
}

__global__ __launch_bounds__(128) void finalize_kernel(
    const float* __restrict__ sums, const unsigned int* __restrict__ counts,
    float* __restrict__ out, int tail, int N)
{
    __shared__ float s_red[NCLS][2];
    const int t = threadIdx.x;           // 128 threads, one per column
    const int lane = t & 63;
    const int wv = t >> 6;

    float cnt1 = 0.f, cnt2 = 0.f;
    float sAll = 0.f, s1 = 0.f, s2 = 0.f;
    #pragma unroll
    for (int rp = 0; rp < REP; rp++) {
        cnt1 += (float)counts[rp * 2 + 0];
        cnt2 += (float)counts[rp * 2 + 1];
        sAll += sums[rp * NCLS * D + 0 * D + t];
        s1   += sums[rp * NCLS * D + 1 * D + t];
        s2   += sums[rp * NCLS * D + 2 * D + t];
    }
    const float cnt0 = (float)N - cnt1 - cnt2;

    float center[NCLS];
    center[0] = (sAll - s1 - s2) / cnt0;
    center[1] = s1 / cnt1;
    center[2] = s2 / cnt2;

    #pragma unroll
    for (int k = 0; k < NCLS; k++) {
        float sq = center[k] * center[k];
        #pragma unroll
        for (int off = 32; off > 0; off >>= 1) sq += __shfl_down(sq, off, 64);
        if (lane == 0) s_red[k][wv] = sq;
    }
    __syncthreads();

    #pragma unroll
    for (int k = 0; k < NCLS; k++) {
        const float norm = sqrtf(s_red[k][0] + s_red[k][1]);
        out[k * D + t] = center[k] / fmaxf(norm, 1e-12f);
    }
    // second tuple output: target = arange(NUM_CLASSES), stored as output dtype
    if (t < tail) out[NCLS * D + t] = (float)t;
}

extern "C" void kernel_launch(void* const* d_in, const int* in_sizes, int n_in,
                              void* d_out, int out_size, void* d_ws, size_t ws_size,
                              hipStream_t stream) {
    const float* feat = (const float*)d_in[0];
    const int* labels = (const int*)d_in[1];
    const int N = in_sizes[1];

    float* sums = (float*)d_ws;
    unsigned int* counts = (unsigned int*)((float*)d_ws + REP * NCLS * D);

    // zero the accumulator workspace every call (harness poisons ws once, never restores)
    hipMemsetAsync(d_ws, 0, (REP * NCLS * D + REP * 2) * sizeof(float), stream);

    const int grid = 2048;
    class_sum_kernel<<<grid, 256, 0, stream>>>(feat, labels, sums, counts, N);

    int tail = out_size - NCLS * D;
    if (tail < 0) tail = 0;
    if (tail > D) tail = D;
    finalize_kernel<<<1, 128, 0, stream>>>(sums, counts, (float*)d_out, tail, N);
}